// Round 10
// baseline (2208.257 us; speedup 1.0000x reference)
//
#include <hip/hip_runtime.h>

#define BB 64
#define SS 2048
#define II 128
#define HH 256
#define OO 128
#define GG 16          // batches per scan block
#define RS 264         // f16 row stride per batch-col in LDS (16B aligned, bank-spread)

typedef _Float16 half8 __attribute__((ext_vector_type(8)));
typedef float    f32x4 __attribute__((ext_vector_type(4)));
typedef _Float16 h2_t  __attribute__((ext_vector_type(2)));

// ---------------------------------------------------------------------------
// Prep: transpose W_ih -> [I][H], W_fc -> [H][O], combine biases,
// pack W_hh into f16 pairs: whh16[j][i] = (f16 W_hh[j][2i], f16 W_hh[j][2i+1])
// ---------------------------------------------------------------------------
__global__ void prep_kernel(const float* __restrict__ W_ih, const float* __restrict__ b_ih,
                            const float* __restrict__ b_hh, const float* __restrict__ W_fc,
                            float* __restrict__ wihT, float* __restrict__ wfcT,
                            float* __restrict__ biasc, unsigned* __restrict__ whh16,
                            const float* __restrict__ W_hh) {
    int idx = blockIdx.x * 256 + threadIdx.x;
    if (idx < HH * II) {            // W_ih [H][I] -> wihT [I][H]
        int j = idx / II, k = idx % II;
        wihT[k * HH + j] = W_ih[idx];
    }
    if (idx < OO * HH) {            // W_fc [O][H] -> wfcT [H][O]
        int j = idx / HH, k = idx % HH;
        wfcT[k * OO + j] = W_fc[idx];
    }
    if (idx < HH * (HH / 2)) {      // W_hh -> packed f16 pairs [256][128]
        int j = idx / (HH / 2), i = idx % (HH / 2);
        union { h2_t h; unsigned u; } pk;
        pk.h.x = (_Float16)W_hh[j * HH + 2 * i];
        pk.h.y = (_Float16)W_hh[j * HH + 2 * i + 1];
        whh16[idx] = pk.u;
    }
    if (idx < HH) biasc[idx] = b_ih[idx] + b_hh[idx];
}

// ---------------------------------------------------------------------------
// Generic row-major GEMM: C[r][j] = sum_k A[r][k] * Wt[k][j] + bias[j]
// 256 threads, 8x8 micro-tile per thread. (unchanged — scan dominates)
// ---------------------------------------------------------------------------
template<int KD, int JD, int RT>
__global__ __launch_bounds__(256, 2)
void gemm_rk(const float* __restrict__ A, const float* __restrict__ Wt,
             const float* __restrict__ bias, float* __restrict__ C) {
    constexpr int KT = 64;
    constexpr int TJ = JD / 8;
    constexpr int TR = RT / 8;
    static_assert(TJ * TR == 256, "bad tiling");

    __shared__ __align__(16) float a_lds[RT][KT];
    __shared__ __align__(16) float w_lds[KT][JD];

    const int tid = threadIdx.x;
    const int tj = tid % TJ;
    const int tr = tid / TJ;
    const long r0 = (long)blockIdx.x * RT;

    float acc[8][8];
#pragma unroll
    for (int r = 0; r < 8; ++r)
#pragma unroll
        for (int j = 0; j < 8; ++j) acc[r][j] = 0.0f;

    for (int kt = 0; kt < KD; kt += KT) {
        {
            constexpr int NF4 = RT * KT / 4;
#pragma unroll
            for (int f = 0; f < NF4 / 256; ++f) {
                int fl = f * 256 + tid;
                int rr = fl / (KT / 4), kk4 = fl % (KT / 4);
                *(float4*)&a_lds[rr][kk4 * 4] =
                    *(const float4*)&A[(r0 + rr) * KD + kt + kk4 * 4];
            }
        }
        {
            constexpr int NF4 = KT * JD / 4;
#pragma unroll
            for (int f = 0; f < NF4 / 256; ++f) {
                int fl = f * 256 + tid;
                int kk = fl / (JD / 4), jj4 = fl % (JD / 4);
                *(float4*)&w_lds[kk][jj4 * 4] =
                    *(const float4*)&Wt[(long)(kt + kk) * JD + jj4 * 4];
            }
        }
        __syncthreads();

#pragma unroll 4
        for (int k4 = 0; k4 < KT; k4 += 4) {
            float4 xv[8];
#pragma unroll
            for (int r = 0; r < 8; ++r)
                xv[r] = *(const float4*)&a_lds[tr * 8 + r][k4];
#pragma unroll
            for (int i = 0; i < 4; ++i) {
                float4 wa = *(const float4*)&w_lds[k4 + i][tj * 8];
                float4 wb = *(const float4*)&w_lds[k4 + i][tj * 8 + 4];
#pragma unroll
                for (int r = 0; r < 8; ++r) {
                    float xs = (i == 0) ? xv[r].x : (i == 1) ? xv[r].y
                             : (i == 2) ? xv[r].z : xv[r].w;
                    acc[r][0] = fmaf(xs, wa.x, acc[r][0]);
                    acc[r][1] = fmaf(xs, wa.y, acc[r][1]);
                    acc[r][2] = fmaf(xs, wa.z, acc[r][2]);
                    acc[r][3] = fmaf(xs, wa.w, acc[r][3]);
                    acc[r][4] = fmaf(xs, wb.x, acc[r][4]);
                    acc[r][5] = fmaf(xs, wb.y, acc[r][5]);
                    acc[r][6] = fmaf(xs, wb.z, acc[r][6]);
                    acc[r][7] = fmaf(xs, wb.w, acc[r][7]);
                }
            }
        }
        __syncthreads();
    }

    float4 b0 = *(const float4*)&bias[tj * 8];
    float4 b1 = *(const float4*)&bias[tj * 8 + 4];
#pragma unroll
    for (int r = 0; r < 8; ++r) {
        long row = r0 + tr * 8 + r;
        float4 o0, o1;
        o0.x = acc[r][0] + b0.x; o0.y = acc[r][1] + b0.y;
        o0.z = acc[r][2] + b0.z; o0.w = acc[r][3] + b0.w;
        o1.x = acc[r][4] + b1.x; o1.y = acc[r][5] + b1.y;
        o1.z = acc[r][6] + b1.z; o1.w = acc[r][7] + b1.w;
        *(float4*)&C[row * JD + tj * 8]     = o0;
        *(float4*)&C[row * JD + tj * 8 + 4] = o1;
    }
}

__device__ __forceinline__ float tanh_fast(float s) {
    // tanh(s) = 1 - 2/(e^{2s}+1); overflow-safe (e=inf -> 1, e=0 -> -1)
    float e = __expf(2.0f * s);
    return 1.0f - __fdividef(2.0f, e + 1.0f);
}

// ---------------------------------------------------------------------------
// Sequential scan v6 (MFMA): H_t[256x16] = tanh(XP_t + W_hh @ H_{t-1}),
// in-place over xproj. 4 blocks (16 batches each) x 512 threads (8 waves).
//
// v1-v5 lesson: per-batch blocks pay a full 256-wide h broadcast + weight
// re-materialization every step (~1600 cyc/step). Batch-blocking amortizes
// both over 16 batches and moves the MACs to the MFMA pipe (AGPR demotion
// becomes FREE: MFMA reads A operands from AGPRs natively).
//
// Wave w owns rows [w*32, w*32+32) = 2 row-tiles. Per step:
//   8 x ds_read_b128 (B frags, H f16 in LDS [col][k], stride 264)
//   16 x mfma_f32_16x16x32_f16 (2 acc chains of 8)
//   + xp add (prefetched depth-2 from global), 8 x tanh,
//   f16 repack -> 2 x 8B LDS writes, fp32 stores to hidden (in-place).
// Fragment maps: D col=l&15,row=(l>>4)*4+reg [m89]; A row=l&15; B col=l&15;
// A/B share the k convention (k=kt*32+(l>>4)*8+j) -> contraction correct
// under any consistent k permutation. ONE barrier per step, double-buffered.
// ---------------------------------------------------------------------------
__global__ __attribute__((amdgpu_waves_per_eu(2, 2))) __launch_bounds__(512)
void rnn_scan(const unsigned* __restrict__ whh16, float* __restrict__ hid) {
    const int bg  = blockIdx.x;          // batch group (16 batches)
    const int tid = threadIdx.x;
    const int w   = tid >> 6;            // wave 0..7
    const int l   = tid & 63;
    const int r16 = l & 15;              // A-row within tile / B,D col
    const int q   = l >> 4;              // k-subgroup / D-row group

    __shared__ __align__(16) _Float16 h16[2][GG][RS];

    // A fragments (weights, f16): rows w*32 + rt*16 + r16, 8 k-tiles
    half8 a_f[2][8];
#pragma unroll
    for (int rt = 0; rt < 2; ++rt) {
        const unsigned* wp = &whh16[(w * 32 + rt * 16 + r16) * (HH / 2)];
#pragma unroll
        for (int kt = 0; kt < 8; ++kt)
            a_f[rt][kt] = *(const half8*)&wp[kt * 16 + q * 4];
    }

    // zero both H buffers (h_{-1} = 0)
    for (int i = tid; i < 2 * GG * RS / 2; i += 512) ((unsigned*)h16)[i] = 0u;

    const int c = r16;                   // batch column
    float* __restrict__ basec = hid + (size_t)(bg * GG + c) * SS * HH;
    const int row0 = w * 32 + q * 4;     // D rows for rt=0 (rt=1: +16)

    // xp prefetch pipeline, depth 2
    f32x4 xA0 = *(const f32x4*)(basec + row0);
    f32x4 xB0 = *(const f32x4*)(basec + row0 + 16);
    f32x4 xA1 = *(const f32x4*)(basec + HH + row0);
    f32x4 xB1 = *(const f32x4*)(basec + HH + row0 + 16);
    __syncthreads();

    int cur = 0;
#pragma unroll 1
    for (int t = 0; t < SS; ++t) {
        // prefetch xp for t+2 (reads precede the in-place overwrite at t)
        f32x4 xA2 = {0.f, 0.f, 0.f, 0.f}, xB2 = xA2;
        if (t + 2 < SS) {
            xA2 = *(const f32x4*)(basec + (size_t)(t + 2) * HH + row0);
            xB2 = *(const f32x4*)(basec + (size_t)(t + 2) * HH + row0 + 16);
        }

        f32x4 acc0 = {0.f, 0.f, 0.f, 0.f}, acc1 = acc0;
#pragma unroll
        for (int kt = 0; kt < 8; ++kt) {
            half8 bf = *(const half8*)&h16[cur][c][kt * 32 + q * 8];
            acc0 = __builtin_amdgcn_mfma_f32_16x16x32_f16(a_f[0][kt], bf, acc0, 0, 0, 0);
            acc1 = __builtin_amdgcn_mfma_f32_16x16x32_f16(a_f[1][kt], bf, acc1, 0, 0, 0);
        }
        acc0 += xA0;
        acc1 += xB0;

        f32x4 h0, h1;
        h0.x = tanh_fast(acc0.x); h0.y = tanh_fast(acc0.y);
        h0.z = tanh_fast(acc0.z); h0.w = tanh_fast(acc0.w);
        h1.x = tanh_fast(acc1.x); h1.y = tanh_fast(acc1.y);
        h1.z = tanh_fast(acc1.z); h1.w = tanh_fast(acc1.w);

        // fp32 hidden (in-place over xproj)
        *(f32x4*)(basec + (size_t)t * HH + row0)      = h0;
        *(f32x4*)(basec + (size_t)t * HH + row0 + 16) = h1;

        // f16 repack into next H buffer: 4 consecutive rows per tile = 8B
        union { _Float16 h[4]; uint2 v; } p0, p1;
        p0.h[0] = (_Float16)h0.x; p0.h[1] = (_Float16)h0.y;
        p0.h[2] = (_Float16)h0.z; p0.h[3] = (_Float16)h0.w;
        p1.h[0] = (_Float16)h1.x; p1.h[1] = (_Float16)h1.y;
        p1.h[2] = (_Float16)h1.z; p1.h[3] = (_Float16)h1.w;
        *(uint2*)&h16[cur ^ 1][c][row0]      = p0.v;
        *(uint2*)&h16[cur ^ 1][c][row0 + 16] = p1.v;

        __syncthreads();
        cur ^= 1;
        xA0 = xA1; xA1 = xA2;
        xB0 = xB1; xB1 = xB2;
    }
}

// ---------------------------------------------------------------------------
extern "C" void kernel_launch(void* const* d_in, const int* in_sizes, int n_in,
                              void* d_out, int out_size, void* d_ws, size_t ws_size,
                              hipStream_t stream) {
    const float* x    = (const float*)d_in[0];
    const float* W_ih = (const float*)d_in[1];
    const float* W_hh = (const float*)d_in[2];
    const float* b_ih = (const float*)d_in[3];
    const float* b_hh = (const float*)d_in[4];
    const float* W_fc = (const float*)d_in[5];
    const float* b_fc = (const float*)d_in[6];

    float* out_fc  = (float*)d_out;                          // [B][S][O]
    float* hidden  = (float*)d_out + (size_t)BB * SS * OO;   // [B][S][H]

    float*    wihT  = (float*)d_ws;                  // [I][H]  32768 f
    float*    wfcT  = wihT + II * HH;                // [H][O]  32768 f
    float*    biasc = wfcT + HH * OO;                // [H]       256 f
    unsigned* whh16 = (unsigned*)(biasc + HH);       // [H][H/2] 32768 u32

    const long NR = (long)BB * SS;                   // 131072 rows

    prep_kernel<<<128, 256, 0, stream>>>(W_ih, b_ih, b_hh, W_fc,
                                         wihT, wfcT, biasc, whh16, W_hh);
    gemm_rk<II, HH, 64><<<NR / 64, 256, 0, stream>>>(x, wihT, biasc, hidden);
    rnn_scan<<<BB / GG, 512, 0, stream>>>(whh16, hidden);
    gemm_rk<HH, OO, 128><<<NR / 128, 256, 0, stream>>>(hidden, wfcT, b_fc, out_fc);
}